// Round 11
// baseline (8703.526 us; speedup 1.0000x reference)
//
#include <hip/hip_runtime.h>
#include <hip/hip_cooperative_groups.h>
#include <math.h>

#define HD     1024
#define TLEN   2048
#define G4H    4096
#define VOUTN  32000
#define NSTEP  50
#define BOS_ID 1
#define EOS_ID 2

// ---- decoder grids ----
#define NBLK   256
#define NTHR   256
#define JPB    (HD / NBLK)     // 4
#define TPB    (TLEN / NBLK)   // 8
#define NBLK_L 500             // k_logits blocks; 500*64 = 32000
#define RPW_L  16

// ---- encoder grid ----
#define ENBLK 64
#define ENTHR 1024
#define EJPB  (HD / ENBLK)   // 16

#define SENTINEL 0xFFFFFFFFu   // -NaN; h=o*tanh(c) can never be this
#define POLL_SLEEP 6           // s_sleep quantum (~160ns): cuts poll fabric traffic ~6x vs 1

// ---- workspace layout (float offsets) ----
#define OFF_GX   ((size_t)0)                          // [TLEN][4H]
#define OFF_HS   (OFF_GX + (size_t)TLEN * G4H)        // [TLEN+1][HD]
#define OFF_HD   (OFF_HS + (size_t)(TLEN + 1) * HD)   // [2][HD] decoder h dbuf
#define OFF_SC   (OFF_HD + 2 * HD)                    // [TLEN] scores
#define OFF_DC   (OFF_SC + TLEN)                      // [HD] context (fallback path)
#define OFF_HTN  (OFF_DC + HD)                        // [HD] ht_new
#define OFF_BMV  (OFF_HTN + HD)                       // [512] block argmax val
#define OFF_BMI  (OFF_BMV + 512)                      // [512] block argmax idx (int)
#define OFF_CT   (OFF_BMI + 512)                      // [HD] decoder cell state
#define OFF_ST   (OFF_CT + HD)                        // [NSTEP+1] packed state (int) +pad
#define OFF_P    (OFF_ST + 64)                        // [HD][TLEN] P matrix (optional)
#define WS_NEED_P ((OFF_P + (size_t)HD * TLEN) * sizeof(float))

#define DEV_SCOPE __HIP_MEMORY_SCOPE_AGENT

__device__ __forceinline__ float dload(const float* p) {
    return __hip_atomic_load(p, __ATOMIC_RELAXED, DEV_SCOPE);
}
__device__ __forceinline__ void dstore(float* p, float v) {
    __hip_atomic_store(p, v, __ATOMIC_RELAXED, DEV_SCOPE);
}

// ============================================================
// Kernel 0: init hs — row 0 zeros (h0), rows 1..TLEN sentinel.
// (TLEN+1) * HD floats = 2049 blocks x 256 threads x float4. Replay-safe.
// ============================================================
__global__ __launch_bounds__(256) void fill_sentinel(float* __restrict__ hsbase)
{
    const size_t i = ((size_t)blockIdx.x * 256 + threadIdx.x) * 4;
    const unsigned v = (i < HD) ? 0u : SENTINEL;   // row 0 = zeros
    uint4 u = make_uint4(v, v, v, v);
    *(uint4*)(hsbase + i) = u;
}

// ============================================================
// Kernel 1: Gx = X @ We_ih^T + be  (unchanged — proven)
// ============================================================
__global__ __launch_bounds__(256) void gx_gemm(
    const int* __restrict__ src_ids,
    const float* __restrict__ emb,
    const float* __restrict__ Wih,
    const float* __restrict__ be,
    float* __restrict__ Gx)
{
    __shared__ float As[128][17];
    __shared__ float Bs[128][17];
    __shared__ int   sid[128];

    const int tid = threadIdx.x;
    const int t0 = blockIdx.x * 128;
    const int r0 = blockIdx.y * 128;

    if (tid < 128) sid[tid] = src_ids[t0 + tid];
    __syncthreads();

    const int tx = tid & 15;
    const int ty = tid >> 4;
    const int lrow = tid >> 1;
    const int lk   = (tid & 1) * 8;

    float acc[8][8];
#pragma unroll
    for (int i = 0; i < 8; ++i)
#pragma unroll
        for (int j = 0; j < 8; ++j) acc[i][j] = 0.f;

    for (int k0 = 0; k0 < HD; k0 += 16) {
        {
            const float* xa = emb + (size_t)sid[lrow] * HD + k0 + lk;
            float4 v0 = *(const float4*)xa;
            float4 v1 = *(const float4*)(xa + 4);
            As[lrow][lk + 0] = v0.x; As[lrow][lk + 1] = v0.y;
            As[lrow][lk + 2] = v0.z; As[lrow][lk + 3] = v0.w;
            As[lrow][lk + 4] = v1.x; As[lrow][lk + 5] = v1.y;
            As[lrow][lk + 6] = v1.z; As[lrow][lk + 7] = v1.w;
            const float* wb = Wih + (size_t)(r0 + lrow) * HD + k0 + lk;
            float4 w0 = *(const float4*)wb;
            float4 w1 = *(const float4*)(wb + 4);
            Bs[lrow][lk + 0] = w0.x; Bs[lrow][lk + 1] = w0.y;
            Bs[lrow][lk + 2] = w0.z; Bs[lrow][lk + 3] = w0.w;
            Bs[lrow][lk + 4] = w1.x; Bs[lrow][lk + 5] = w1.y;
            Bs[lrow][lk + 6] = w1.z; Bs[lrow][lk + 7] = w1.w;
        }
        __syncthreads();
#pragma unroll
        for (int kk = 0; kk < 16; ++kk) {
            float a[8], bv[8];
#pragma unroll
            for (int i = 0; i < 8; ++i) a[i]  = As[ty * 8 + i][kk];
#pragma unroll
            for (int j = 0; j < 8; ++j) bv[j] = Bs[tx * 8 + j][kk];
#pragma unroll
            for (int i = 0; i < 8; ++i)
#pragma unroll
                for (int j = 0; j < 8; ++j)
                    acc[i][j] = fmaf(a[i], bv[j], acc[i][j]);
        }
        __syncthreads();
    }

    float bev[8];
#pragma unroll
    for (int j = 0; j < 8; ++j) bev[j] = be[r0 + tx * 8 + j];
#pragma unroll
    for (int i = 0; i < 8; ++i) {
        const int t = t0 + ty * 8 + i;
        float* dst = Gx + (size_t)t * G4H + r0 + tx * 8;
#pragma unroll
        for (int j = 0; j < 8; ++j) dst[j] = acc[i][j] + bev[j];
    }
}

// ============================================================
// Kernel 2: encoder — R10 structure verbatim; only POLL_SLEEP changed (1->6).
// ============================================================
__global__ __launch_bounds__(1024, 4) void enc_kernel(
    const float* __restrict__ Whh,
    const float* __restrict__ Gx,
    float* __restrict__ wsf)
{
    float* hs   = wsf + OFF_HS;
    float* hd   = wsf + OFF_HD;
    float* cdec = wsf + OFF_CT;
    int*   st   = (int*)(wsf + OFF_ST);

    const int b    = blockIdx.x;
    const int tid  = threadIdx.x;
    const int w    = tid >> 6;
    const int lane = tid & 63;
    const int j0   = b * EJPB;
    const int g    = w >> 2;
    const int e0   = (w & 3) * 4;

    __shared__ float bufH[HD];
    __shared__ float g_s[64];
    __shared__ float c_s[EJPB];
    __shared__ float gxbuf[2][64];

    float wreg[4][16];
#pragma unroll
    for (int d = 0; d < 4; ++d) {
        const int grow = g * HD + j0 + e0 + d;
        const float* src = Whh + (size_t)grow * HD + lane;
#pragma unroll
        for (int q = 0; q < 16; ++q) wreg[d][q] = src[q * 64];
    }

    if (tid < EJPB) c_s[tid] = 0.f;

    if (tid >= 64 && tid < 128) {
        const int idx = tid - 64;
        gxbuf[0][idx] = Gx[(size_t)0 * G4H + (idx >> 4) * HD + j0 + (idx & 15)];
    }

    for (int t = 0; t < TLEN; ++t) {
        // poll own element (coalesced, 1 load/thread); longer sleep quantum
        // cuts the fabric-level poll flood that was contending with the
        // producers' stores (R10 VALUBusy 3.95% = poll spin).
        {
            const float* src = hs + (size_t)t * HD + tid;
            float v = dload(src);
            while (__float_as_uint(v) == SENTINEL) {
                __builtin_amdgcn_s_sleep(POLL_SLEEP);
                v = dload(src);
            }
            bufH[tid] = v;
        }
        __syncthreads();   // barrier A

        if (tid >= 64 && tid < 128 && t + 1 < TLEN) {
            const int idx = tid - 64;
            gxbuf[(t + 1) & 1][idx] =
                Gx[(size_t)(t + 1) * G4H + (idx >> 4) * HD + j0 + (idx & 15)];
        }

        float acc[4];
#pragma unroll
        for (int d = 0; d < 4; ++d) {
            float a = 0.f;
#pragma unroll
            for (int q = 0; q < 16; ++q)
                a = fmaf(wreg[d][q], bufH[q * 64 + lane], a);
#pragma unroll
            for (int off = 32; off > 0; off >>= 1) a += __shfl_down(a, off);
            acc[d] = a;
        }
        if (lane == 0) {
#pragma unroll
            for (int d = 0; d < 4; ++d) g_s[g * 16 + e0 + d] = acc[d];
        }
        __syncthreads();   // barrier B

        if (tid < EJPB) {
            const int j = j0 + tid;
            const float gi = g_s[tid]      + gxbuf[t & 1][tid];
            const float gf = g_s[16 + tid] + gxbuf[t & 1][16 + tid];
            const float gg = g_s[32 + tid] + gxbuf[t & 1][32 + tid];
            const float go = g_s[48 + tid] + gxbuf[t & 1][48 + tid];
            const float i_ = 1.f / (1.f + expf(-gi));
            const float f_ = 1.f / (1.f + expf(-gf));
            const float o_ = 1.f / (1.f + expf(-go));
            const float g2 = tanhf(gg);
            const float c2 = f_ * c_s[tid] + i_ * g2;
            c_s[tid] = c2;
            dstore(hs + (size_t)(t + 1) * HD + j, o_ * tanhf(c2));  // store IS the signal
        }
    }

    if (tid < EJPB) {
        cdec[j0 + tid] = c_s[tid];
        hd[j0 + tid]   = hs[(size_t)TLEN * HD + j0 + tid];
    }
    if (b == 0 && tid == 0) st[0] = BOS_ID;
}

// ============================================================
// Kernel 2b: P[j][t] = dot(W_attn[j, 0:HD], hs[t+1])  — tile GEMM (proven)
// ============================================================
__global__ __launch_bounds__(256) void p_gemm(
    const float* __restrict__ Wattn,
    const float* __restrict__ hs,
    float* __restrict__ P)
{
    __shared__ float As[128][17];
    __shared__ float Bs[128][17];

    const int tid = threadIdx.x;
    const int j0 = blockIdx.x * 128;
    const int t0 = blockIdx.y * 128;
    const int tx = tid & 15;
    const int ty = tid >> 4;
    const int lrow = tid >> 1;
    const int lk   = (tid & 1) * 8;

    float acc[8][8];
#pragma unroll
    for (int i = 0; i < 8; ++i)
#pragma unroll
        for (int j = 0; j < 8; ++j) acc[i][j] = 0.f;

    for (int k0 = 0; k0 < HD; k0 += 16) {
        {
            const float* wa = Wattn + (size_t)(j0 + lrow) * (2 * HD) + k0 + lk;
            float4 v0 = *(const float4*)wa;
            float4 v1 = *(const float4*)(wa + 4);
            As[lrow][lk + 0] = v0.x; As[lrow][lk + 1] = v0.y;
            As[lrow][lk + 2] = v0.z; As[lrow][lk + 3] = v0.w;
            As[lrow][lk + 4] = v1.x; As[lrow][lk + 5] = v1.y;
            As[lrow][lk + 6] = v1.z; As[lrow][lk + 7] = v1.w;
            const float* hb = hs + (size_t)(t0 + lrow + 1) * HD + k0 + lk;
            float4 h0 = *(const float4*)hb;
            float4 h1 = *(const float4*)(hb + 4);
            Bs[lrow][lk + 0] = h0.x; Bs[lrow][lk + 1] = h0.y;
            Bs[lrow][lk + 2] = h0.z; Bs[lrow][lk + 3] = h0.w;
            Bs[lrow][lk + 4] = h1.x; Bs[lrow][lk + 5] = h1.y;
            Bs[lrow][lk + 6] = h1.z; Bs[lrow][lk + 7] = h1.w;
        }
        __syncthreads();
#pragma unroll
        for (int kk = 0; kk < 16; ++kk) {
            float a[8], bv[8];
#pragma unroll
            for (int i = 0; i < 8; ++i) a[i]  = As[ty * 8 + i][kk];
#pragma unroll
            for (int j = 0; j < 8; ++j) bv[j] = Bs[tx * 8 + j][kk];
#pragma unroll
            for (int i = 0; i < 8; ++i)
#pragma unroll
                for (int j = 0; j < 8; ++j)
                    acc[i][j] = fmaf(a[i], bv[j], acc[i][j]);
        }
        __syncthreads();
    }

#pragma unroll
    for (int i = 0; i < 8; ++i) {
        float* dst = P + (size_t)(j0 + ty * 8 + i) * TLEN + t0 + tx * 8;
#pragma unroll
        for (int j = 0; j < 8; ++j) dst[j] = acc[i][j];
    }
}

// ============================================================
// K1: gates — folds previous step's argmax (proven)
// ============================================================
__global__ __launch_bounds__(256) void k_gates(
    const float* __restrict__ embT,
    const float* __restrict__ Wdih,
    const float* __restrict__ Wdhh,
    const float* __restrict__ bdv,
    float* __restrict__ wsf,
    float* __restrict__ out, int s)
{
    float* hd   = wsf + OFF_HD;
    float* cdec = wsf + OFF_CT;
    int*   st   = (int*)(wsf + OFF_ST);
    const float* bmv = wsf + OFF_BMV;
    const int*   bmi = (const int*)(wsf + OFF_BMI);

    const int b    = blockIdx.x;
    const int tid  = threadIdx.x;
    const int w    = tid >> 6;
    const int lane = tid & 63;
    const int j0   = b * JPB;

    const float* hcur = hd + (s & 1) * HD;
    float*       hnxt = hd + ((s + 1) & 1) * HD;

    __shared__ float bufAB[2 * HD];
    __shared__ float g_s[4 * JPB];
    __shared__ float rv[NTHR];
    __shared__ int   ri[NTHR];
    __shared__ int   s_wid;

    for (int i = tid; i < HD; i += NTHR) bufAB[HD + i] = hcur[i];

    if (s == 0) {
        if (tid == 0) s_wid = st[0] & 0xFFFF;
        __syncthreads();
    } else {
        float v1 = bmv[tid]; int i1 = bmi[tid];
        if (tid + 256 < NBLK_L) {
            float v2 = bmv[tid + 256]; int i2 = bmi[tid + 256];
            if (v2 > v1 || (v2 == v1 && i2 < i1)) { v1 = v2; i1 = i2; }
        }
        rv[tid] = v1; ri[tid] = i1;
        __syncthreads();
        for (int s2 = 128; s2 > 0; s2 >>= 1) {
            if (tid < s2) {
                if (rv[tid + s2] > rv[tid] ||
                    (rv[tid + s2] == rv[tid] && ri[tid + s2] < ri[tid])) {
                    rv[tid] = rv[tid + s2]; ri[tid] = ri[tid + s2];
                }
            }
            __syncthreads();
        }
        if (tid == 0) {
            const int nid   = ri[0];
            const int prev  = st[s - 1];
            const int dprev = (prev >> 16) & 1;
            const int dnew  = dprev | (nid == EOS_ID);
            s_wid = nid;
            if (b == 0) {
                out[s - 1] = dprev ? 0.f : (float)nid;
                st[s] = (dnew << 16) | nid;
            }
        }
        __syncthreads();
    }

    const float* x = embT + (size_t)s_wid * HD;
    for (int i = tid; i < HD; i += NTHR) bufAB[i] = x[i];
    __syncthreads();

    const float4* buf4 = (const float4*)bufAB;
#pragma unroll
    for (int d = 0; d < 4; ++d) {
        const int grow = w * HD + j0 + d;
        const float4* wi4 = (const float4*)(Wdih + (size_t)grow * HD);
        const float4* wh4 = (const float4*)(Wdhh + (size_t)grow * HD);
        float4 a4 = make_float4(0.f, 0.f, 0.f, 0.f);
#pragma unroll
        for (int q = 0; q < 4; ++q) {
            float4 wv = wi4[q * 64 + lane], xv = buf4[q * 64 + lane];
            a4.x = fmaf(wv.x, xv.x, a4.x); a4.y = fmaf(wv.y, xv.y, a4.y);
            a4.z = fmaf(wv.z, xv.z, a4.z); a4.w = fmaf(wv.w, xv.w, a4.w);
            float4 wv2 = wh4[q * 64 + lane], hv = buf4[256 + q * 64 + lane];
            a4.x = fmaf(wv2.x, hv.x, a4.x); a4.y = fmaf(wv2.y, hv.y, a4.y);
            a4.z = fmaf(wv2.z, hv.z, a4.z); a4.w = fmaf(wv2.w, hv.w, a4.w);
        }
        float a = (a4.x + a4.y) + (a4.z + a4.w);
#pragma unroll
        for (int off = 32; off > 0; off >>= 1) a += __shfl_down(a, off);
        if (lane == 0) g_s[w * 4 + d] = a;
    }
    __syncthreads();

    if (tid < JPB) {
        const int j = j0 + tid;
        const float gi = g_s[0 * 4 + tid] + bdv[0 * HD + j];
        const float gf = g_s[1 * 4 + tid] + bdv[1 * HD + j];
        const float gg = g_s[2 * 4 + tid] + bdv[2 * HD + j];
        const float go = g_s[3 * 4 + tid] + bdv[3 * HD + j];
        const float i_ = 1.f / (1.f + expf(-gi));
        const float f_ = 1.f / (1.f + expf(-gf));
        const float o_ = 1.f / (1.f + expf(-go));
        const float g2 = tanhf(gg);
        const float c2 = f_ * cdec[j] + i_ * g2;
        cdec[j] = c2;
        hnxt[j] = o_ * tanhf(c2);
    }
}

// K2: attention scores (unchanged)
__global__ __launch_bounds__(256) void k_scores(float* __restrict__ wsf, int s)
{
    const float* hs = wsf + OFF_HS;
    const float* hnxt = wsf + OFF_HD + (size_t)((s + 1) & 1) * HD;
    float* sc = wsf + OFF_SC;

    const int b    = blockIdx.x;
    const int tid  = threadIdx.x;
    const int w    = tid >> 6;
    const int lane = tid & 63;

    __shared__ float bufH[HD];
    const float4* buf4 = (const float4*)bufH;
    for (int i = tid; i < HD; i += NTHR) bufH[i] = hnxt[i];
    __syncthreads();

#pragma unroll
    for (int d = 0; d < 2; ++d) {
        const int t = b * TPB + w * 2 + d;
        const float4* hr4 = (const float4*)(hs + (size_t)(t + 1) * HD);
        float4 a4 = make_float4(0.f, 0.f, 0.f, 0.f);
#pragma unroll
        for (int q = 0; q < 4; ++q) {
            float4 hv = hr4[q * 64 + lane], bv = buf4[q * 64 + lane];
            a4.x = fmaf(hv.x, bv.x, a4.x); a4.y = fmaf(hv.y, bv.y, a4.y);
            a4.z = fmaf(hv.z, bv.z, a4.z); a4.w = fmaf(hv.w, bv.w, a4.w);
        }
        float a = (a4.x + a4.y) + (a4.z + a4.w);
#pragma unroll
        for (int off = 32; off > 0; off >>= 1) a += __shfl_down(a, off);
        if (lane == 0) sc[t] = a;
    }
}

// K3 (P path): fused softmax + context-via-P + W_attn[:,H:]·ht + tanh (proven)
__global__ __launch_bounds__(256) void k_ctxattn(
    const float* __restrict__ Wattn,
    const float* __restrict__ battn,
    float* __restrict__ wsf,
    const float* __restrict__ P, int s)
{
    const float* sc = wsf + OFF_SC;
    const float* hnxt = wsf + OFF_HD + (size_t)((s + 1) & 1) * HD;
    float* htn = wsf + OFF_HTN;

    const int b    = blockIdx.x;
    const int tid  = threadIdx.x;
    const int w    = tid >> 6;
    const int lane = tid & 63;
    const int j0   = b * JPB;

    __shared__ float sc_s[TLEN];
    __shared__ float bufH[HD];
    __shared__ float red[NTHR];

    for (int t = tid; t < TLEN; t += NTHR) sc_s[t] = sc[t];
    for (int i = tid; i < HD; i += NTHR) bufH[i] = hnxt[i];
    __syncthreads();

    float lm = -INFINITY;
    for (int t = tid; t < TLEN; t += NTHR) lm = fmaxf(lm, sc_s[t]);
    red[tid] = lm; __syncthreads();
    for (int s2 = NTHR / 2; s2 > 0; s2 >>= 1) {
        if (tid < s2) red[tid] = fmaxf(red[tid], red[tid + s2]);
        __syncthreads();
    }
    const float m = red[0]; __syncthreads();
    float lz = 0.f;
    for (int t = tid; t < TLEN; t += NTHR) lz += __expf(sc_s[t] - m);
    red[tid] = lz; __syncthreads();
    for (int s2 = NTHR / 2; s2 > 0; s2 >>= 1) {
        if (tid < s2) red[tid] += red[tid + s2];
        __syncthreads();
    }
    const float Zi = 1.f / red[0]; __syncthreads();

    const int j = j0 + w;
    float a = 0.f;
    const float* Pr = P + (size_t)j * TLEN;
#pragma unroll
    for (int it = 0; it < TLEN / 64; ++it) {
        const int t = lane + it * 64;
        a = fmaf(__expf(sc_s[t] - m) * Zi, Pr[t], a);
    }
    const float4* wr4 = (const float4*)(Wattn + (size_t)j * (2 * HD) + HD);
    const float4* buf4 = (const float4*)bufH;
    float4 a4 = make_float4(0.f, 0.f, 0.f, 0.f);
#pragma unroll
    for (int q = 0; q < 4; ++q) {
        float4 wv = wr4[q * 64 + lane], hv = buf4[q * 64 + lane];
        a4.x = fmaf(wv.x, hv.x, a4.x); a4.y = fmaf(wv.y, hv.y, a4.y);
        a4.z = fmaf(wv.z, hv.z, a4.z); a4.w = fmaf(wv.w, hv.w, a4.w);
    }
    a += (a4.x + a4.y) + (a4.z + a4.w);
#pragma unroll
    for (int off = 32; off > 0; off >>= 1) a += __shfl_down(a, off);
    if (lane == 0) htn[j] = tanhf(a + battn[j]);
}

// K3-fallback: softmax + context slice — proven
__global__ __launch_bounds__(256) void k_ctx_fb(float* __restrict__ wsf)
{
    const float* hs = wsf + OFF_HS;
    const float* sc = wsf + OFF_SC;
    float* dctx = wsf + OFF_DC;

    const int b    = blockIdx.x;
    const int tid  = threadIdx.x;
    const int w    = tid >> 6;
    const int lane = tid & 63;
    const int j0   = b * JPB;

    __shared__ float sc_s[TLEN];
    __shared__ float red[NTHR];

    for (int t = tid; t < TLEN; t += NTHR) sc_s[t] = sc[t];
    __syncthreads();

    float lm = -INFINITY;
    for (int t = tid; t < TLEN; t += NTHR) lm = fmaxf(lm, sc_s[t]);
    red[tid] = lm; __syncthreads();
    for (int s2 = NTHR / 2; s2 > 0; s2 >>= 1) {
        if (tid < s2) red[tid] = fmaxf(red[tid], red[tid + s2]);
        __syncthreads();
    }
    const float m = red[0]; __syncthreads();
    float lz = 0.f;
    for (int t = tid; t < TLEN; t += NTHR) lz += __expf(sc_s[t] - m);
    red[tid] = lz; __syncthreads();
    for (int s2 = NTHR / 2; s2 > 0; s2 >>= 1) {
        if (tid < s2) red[tid] += red[tid + s2];
        __syncthreads();
    }
    const float Zi = 1.f / red[0]; __syncthreads();

    const int j = j0 + w;
    float a = 0.f;
#pragma unroll
    for (int it = 0; it < TLEN / 64; ++it) {
        const int t = lane + it * 64;
        a = fmaf(__expf(sc_s[t] - m) * Zi, hs[(size_t)(t + 1) * HD + j], a);
    }
#pragma unroll
    for (int off = 32; off > 0; off >>= 1) a += __shfl_down(a, off);
    if (lane == 0) dctx[j] = a;
}

// K4-fallback: ht_new (proven)
__global__ __launch_bounds__(256) void k_attn(
    const float* __restrict__ Wattn,
    const float* __restrict__ battn,
    float* __restrict__ wsf, int s)
{
    const float* dctx = wsf + OFF_DC;
    const float* hnxt = wsf + OFF_HD + (size_t)((s + 1) & 1) * HD;
    float* htn = wsf + OFF_HTN;

    const int b    = blockIdx.x;
    const int tid  = threadIdx.x;
    const int w    = tid >> 6;
    const int lane = tid & 63;
    const int j0   = b * JPB;

    __shared__ float bufAB[2 * HD];
    const float4* buf4 = (const float4*)bufAB;
    for (int i = tid; i < HD; i += NTHR) {
        bufAB[i]      = dctx[i];
        bufAB[HD + i] = hnxt[i];
    }
    __syncthreads();

    const int j = j0 + w;
    const float4* wr4 = (const float4*)(Wattn + (size_t)j * (2 * HD));
    float4 a4 = make_float4(0.f, 0.f, 0.f, 0.f);
#pragma unroll
    for (int q = 0; q < 8; ++q) {
        float4 wv = wr4[q * 64 + lane], bv = buf4[q * 64 + lane];
        a4.x = fmaf(wv.x, bv.x, a4.x); a4.y = fmaf(wv.y, bv.y, a4.y);
        a4.z = fmaf(wv.z, bv.z, a4.z); a4.w = fmaf(wv.w, bv.w, a4.w);
    }
    float a = (a4.x + a4.y) + (a4.z + a4.w);
#pragma unroll
    for (int off = 32; off > 0; off >>= 1) a += __shfl_down(a, off);
    if (lane == 0) htn[j] = tanhf(a + battn[j]);
}

// K5: logits + per-block argmax, with done fast-path (proven R10)
__global__ __launch_bounds__(256) void k_logits(
    const float* __restrict__ Wout,
    const float* __restrict__ bout,
    float* __restrict__ wsf,
    float* __restrict__ out, int s)
{
    const float* htn = wsf + OFF_HTN;
    float* bmv = wsf + OFF_BMV;
    int*   bmi = (int*)(wsf + OFF_BMI);
    const int* st = (const int*)(wsf + OFF_ST);

    const int b    = blockIdx.x;
    const int tid  = threadIdx.x;
    const int w    = tid >> 6;
    const int lane = tid & 63;

    __shared__ float bufH[HD];
    __shared__ float red[4];
    __shared__ int   redi[4];
    const float4* buf4 = (const float4*)bufH;

    const int donev = (st[s] >> 16) & 1;

    if (donev) {
        if (tid < 64) out[NSTEP + (size_t)s * VOUTN + b * 64 + tid] = 0.f;
        if (tid == 0) { bmv[b] = -INFINITY; bmi[b] = 0; }
        return;
    }

    for (int i = tid; i < HD; i += NTHR) bufH[i] = htn[i];
    __syncthreads();

    const int rbeg = b * 64 + w * RPW_L;
    float bv = -INFINITY; int bi = 0x7fffffff;
    for (int r = rbeg; r < rbeg + RPW_L; r += 2) {
        const float4* w0 = (const float4*)(Wout + (size_t)r * HD);
        const float4* w1 = (const float4*)(Wout + (size_t)(r + 1) * HD);
        float4 a04 = make_float4(0.f, 0.f, 0.f, 0.f);
        float4 a14 = make_float4(0.f, 0.f, 0.f, 0.f);
#pragma unroll
        for (int q = 0; q < 4; ++q) {
            float4 hv = buf4[q * 64 + lane];
            float4 x0 = w0[q * 64 + lane];
            float4 x1 = w1[q * 64 + lane];
            a04.x = fmaf(x0.x, hv.x, a04.x); a04.y = fmaf(x0.y, hv.y, a04.y);
            a04.z = fmaf(x0.z, hv.z, a04.z); a04.w = fmaf(x0.w, hv.w, a04.w);
            a14.x = fmaf(x1.x, hv.x, a14.x); a14.y = fmaf(x1.y, hv.y, a14.y);
            a14.z = fmaf(x1.z, hv.z, a14.z); a14.w = fmaf(x1.w, hv.w, a14.w);
        }
        float a0 = (a04.x + a04.y) + (a04.z + a04.w);
        float a1 = (a14.x + a14.y) + (a14.z + a14.w);
#pragma unroll
        for (int off = 32; off > 0; off >>= 1) {
            a0 += __shfl_down(a0, off);
            a1 += __shfl_down(a1, off);
        }
        if (lane == 0) {
            a0 += bout[r];
            a1 += bout[r + 1];
            out[NSTEP + (size_t)s * VOUTN + r]     = a0;
            out[NSTEP + (size_t)s * VOUTN + r + 1] = a1;
            if (a0 > bv) { bv = a0; bi = r; }
            if (a1 > bv) { bv = a1; bi = r + 1; }
        }
    }
    if (lane == 0) { red[w] = bv; redi[w] = bi; }
    __syncthreads();
    if (tid == 0) {
        float v = red[0]; int ii = redi[0];
#pragma unroll
        for (int q = 1; q < 4; ++q)
            if (red[q] > v || (red[q] == v && redi[q] < ii)) { v = red[q]; ii = redi[q]; }
        bmv[b] = v; bmi[b] = ii;
    }
}

// K6 (final only): global argmax for step 49's token
__global__ __launch_bounds__(256) void k_amax_final(
    float* __restrict__ wsf, float* __restrict__ out)
{
    const float* bmv = wsf + OFF_BMV;
    const int*   bmi = (const int*)(wsf + OFF_BMI);
    const int*   st  = (const int*)(wsf + OFF_ST);

    const int tid = threadIdx.x;
    __shared__ float red[NTHR];
    __shared__ int   redi[NTHR];

    float v1 = bmv[tid]; int i1 = bmi[tid];
    if (tid + 256 < NBLK_L) {
        float v2 = bmv[tid + 256]; int i2 = bmi[tid + 256];
        if (v2 > v1 || (v2 == v1 && i2 < i1)) { v1 = v2; i1 = i2; }
    }
    red[tid] = v1; redi[tid] = i1;
    __syncthreads();
    for (int s2 = 128; s2 > 0; s2 >>= 1) {
        if (tid < s2) {
            if (red[tid + s2] > red[tid] ||
                (red[tid + s2] == red[tid] && redi[tid + s2] < redi[tid])) {
                red[tid] = red[tid + s2]; redi[tid] = redi[tid + s2];
            }
        }
        __syncthreads();
    }
    if (tid == 0) {
        const int nid   = redi[0];
        const int donev = (st[NSTEP - 1] >> 16) & 1;
        out[NSTEP - 1] = donev ? 0.f : (float)nid;
    }
}

extern "C" void kernel_launch(void* const* d_in, const int* in_sizes, int n_in,
                              void* d_out, int out_size, void* d_ws, size_t ws_size,
                              hipStream_t stream) {
    (void)in_sizes; (void)n_in; (void)out_size;
    const int*   src_ids = (const int*)  d_in[0];
    const float* emb_in  = (const float*)d_in[1];
    const float* We_ih   = (const float*)d_in[2];
    const float* We_hh   = (const float*)d_in[3];
    const float* be      = (const float*)d_in[4];
    const float* emb_tgt = (const float*)d_in[5];
    const float* Wd_ih   = (const float*)d_in[6];
    const float* Wd_hh   = (const float*)d_in[7];
    const float* bd      = (const float*)d_in[8];
    const float* W_attn  = (const float*)d_in[9];
    const float* b_attn  = (const float*)d_in[10];
    const float* W_out   = (const float*)d_in[11];
    const float* b_out   = (const float*)d_in[12];

    float* outp = (float*)d_out;
    float* wsf  = (float*)d_ws;

    const bool use_P = (ws_size >= WS_NEED_P);

    // deterministic init every call: hs row 0 zeros + rows 1..TLEN sentinel
    fill_sentinel<<<TLEN + 1, 256, 0, stream>>>(wsf + OFF_HS);

    // Phase 1: Gx = X @ We_ih^T + be
    dim3 g1(TLEN / 128, G4H / 128);
    gx_gemm<<<g1, 256, 0, stream>>>(src_ids, emb_in, We_ih, be, wsf + OFF_GX);

    // Phase 2: encoder (cooperative; sentinel data-poll inside)
    {
        const float* a_Whh = We_hh;
        const float* a_Gx  = wsf + OFF_GX;
        float* a_ws  = wsf;
        void* args[] = { &a_Whh, &a_Gx, &a_ws };
        hipLaunchCooperativeKernel(reinterpret_cast<void*>(enc_kernel),
                                   dim3(ENBLK), dim3(ENTHR), args, 0, stream);
    }

    // Phase 2b: P = W_attn[:, :H] @ hs[1:].T  (if workspace allows)
    if (use_P)
        p_gemm<<<dim3(HD / 128, TLEN / 128), 256, 0, stream>>>(
            W_attn, wsf + OFF_HS, wsf + OFF_P);

    // Phase 3: decoder — 4 kernels per step (P path) or 5 (fallback)
    for (int s = 0; s < NSTEP; ++s) {
        k_gates <<<NBLK,   NTHR, 0, stream>>>(emb_tgt, Wd_ih, Wd_hh, bd, wsf, outp, s);
        k_scores<<<NBLK,   NTHR, 0, stream>>>(wsf, s);
        if (use_P) {
            k_ctxattn<<<NBLK, NTHR, 0, stream>>>(W_attn, b_attn, wsf, wsf + OFF_P, s);
        } else {
            k_ctx_fb<<<NBLK, NTHR, 0, stream>>>(wsf);
            k_attn  <<<NBLK, NTHR, 0, stream>>>(W_attn, b_attn, wsf, s);
        }
        k_logits<<<NBLK_L, NTHR, 0, stream>>>(W_out, b_out, wsf, outp, s);
    }
    k_amax_final<<<1, NTHR, 0, stream>>>(wsf, outp);
}

// Round 12
// 8437.581 us; speedup vs baseline: 1.0315x; 1.0315x over previous
//
#include <hip/hip_runtime.h>
#include <hip/hip_cooperative_groups.h>
#include <math.h>

#define HD     1024
#define TLEN   2048
#define G4H    4096
#define VOUTN  32000
#define NSTEP  50
#define BOS_ID 1
#define EOS_ID 2

// ---- decoder grids ----
#define NBLK   256
#define NTHR   256
#define JPB    (HD / NBLK)     // 4
#define TPB    (TLEN / NBLK)   // 8
#define NBLK_L 500             // k_logits blocks; 500*64 = 32000
#define RPW_L  16

// ---- encoder grid ----
#define ENBLK 64
#define ENTHR 1024
#define EJPB  (HD / ENBLK)   // 16

#define SENTINEL 0xFFFFFFFFu   // -NaN; h=o*tanh(c) can never be this
#define POLL_SLEEP 1           // REVERT to R10 (proven best). sleep=6 was a null/regression (R11).

// ---- workspace layout (float offsets) ----
#define OFF_GX   ((size_t)0)                          // [TLEN][4H]
#define OFF_HS   (OFF_GX + (size_t)TLEN * G4H)        // [TLEN+1][HD]
#define OFF_HD   (OFF_HS + (size_t)(TLEN + 1) * HD)   // [2][HD] decoder h dbuf
#define OFF_SC   (OFF_HD + 2 * HD)                    // [TLEN] scores
#define OFF_DC   (OFF_SC + TLEN)                      // [HD] context (fallback path)
#define OFF_HTN  (OFF_DC + HD)                        // [HD] ht_new
#define OFF_BMV  (OFF_HTN + HD)                       // [512] block argmax val
#define OFF_BMI  (OFF_BMV + 512)                      // [512] block argmax idx (int)
#define OFF_CT   (OFF_BMI + 512)                      // [HD] decoder cell state
#define OFF_ST   (OFF_CT + HD)                        // [NSTEP+1] packed state (int) +pad
#define OFF_P    (OFF_ST + 64)                        // [HD][TLEN] P matrix (optional)
#define WS_NEED_P ((OFF_P + (size_t)HD * TLEN) * sizeof(float))

#define DEV_SCOPE __HIP_MEMORY_SCOPE_AGENT

__device__ __forceinline__ float dload(const float* p) {
    return __hip_atomic_load(p, __ATOMIC_RELAXED, DEV_SCOPE);
}
__device__ __forceinline__ void dstore(float* p, float v) {
    __hip_atomic_store(p, v, __ATOMIC_RELAXED, DEV_SCOPE);
}

// ============================================================
// Kernel 0: init hs — row 0 zeros (h0), rows 1..TLEN sentinel. Replay-safe.
// ============================================================
__global__ __launch_bounds__(256) void fill_sentinel(float* __restrict__ hsbase)
{
    const size_t i = ((size_t)blockIdx.x * 256 + threadIdx.x) * 4;
    const unsigned v = (i < HD) ? 0u : SENTINEL;   // row 0 = zeros
    uint4 u = make_uint4(v, v, v, v);
    *(uint4*)(hsbase + i) = u;
}

// ============================================================
// Kernel 1: Gx = X @ We_ih^T + be  (proven)
// ============================================================
__global__ __launch_bounds__(256) void gx_gemm(
    const int* __restrict__ src_ids,
    const float* __restrict__ emb,
    const float* __restrict__ Wih,
    const float* __restrict__ be,
    float* __restrict__ Gx)
{
    __shared__ float As[128][17];
    __shared__ float Bs[128][17];
    __shared__ int   sid[128];

    const int tid = threadIdx.x;
    const int t0 = blockIdx.x * 128;
    const int r0 = blockIdx.y * 128;

    if (tid < 128) sid[tid] = src_ids[t0 + tid];
    __syncthreads();

    const int tx = tid & 15;
    const int ty = tid >> 4;
    const int lrow = tid >> 1;
    const int lk   = (tid & 1) * 8;

    float acc[8][8];
#pragma unroll
    for (int i = 0; i < 8; ++i)
#pragma unroll
        for (int j = 0; j < 8; ++j) acc[i][j] = 0.f;

    for (int k0 = 0; k0 < HD; k0 += 16) {
        {
            const float* xa = emb + (size_t)sid[lrow] * HD + k0 + lk;
            float4 v0 = *(const float4*)xa;
            float4 v1 = *(const float4*)(xa + 4);
            As[lrow][lk + 0] = v0.x; As[lrow][lk + 1] = v0.y;
            As[lrow][lk + 2] = v0.z; As[lrow][lk + 3] = v0.w;
            As[lrow][lk + 4] = v1.x; As[lrow][lk + 5] = v1.y;
            As[lrow][lk + 6] = v1.z; As[lrow][lk + 7] = v1.w;
            const float* wb = Wih + (size_t)(r0 + lrow) * HD + k0 + lk;
            float4 w0 = *(const float4*)wb;
            float4 w1 = *(const float4*)(wb + 4);
            Bs[lrow][lk + 0] = w0.x; Bs[lrow][lk + 1] = w0.y;
            Bs[lrow][lk + 2] = w0.z; Bs[lrow][lk + 3] = w0.w;
            Bs[lrow][lk + 4] = w1.x; Bs[lrow][lk + 5] = w1.y;
            Bs[lrow][lk + 6] = w1.z; Bs[lrow][lk + 7] = w1.w;
        }
        __syncthreads();
#pragma unroll
        for (int kk = 0; kk < 16; ++kk) {
            float a[8], bv[8];
#pragma unroll
            for (int i = 0; i < 8; ++i) a[i]  = As[ty * 8 + i][kk];
#pragma unroll
            for (int j = 0; j < 8; ++j) bv[j] = Bs[tx * 8 + j][kk];
#pragma unroll
            for (int i = 0; i < 8; ++i)
#pragma unroll
                for (int j = 0; j < 8; ++j)
                    acc[i][j] = fmaf(a[i], bv[j], acc[i][j]);
        }
        __syncthreads();
    }

    float bev[8];
#pragma unroll
    for (int j = 0; j < 8; ++j) bev[j] = be[r0 + tx * 8 + j];
#pragma unroll
    for (int i = 0; i < 8; ++i) {
        const int t = t0 + ty * 8 + i;
        float* dst = Gx + (size_t)t * G4H + r0 + tx * 8;
#pragma unroll
        for (int j = 0; j < 8; ++j) dst[j] = acc[i][j] + bev[j];
    }
}

// ============================================================
// Kernel 2: encoder — R10 structure verbatim (proven best: 5.47 ms).
// Coalesced 1-load/thread sentinel poll; g_s; coalesced tid<16 publish;
// Gx double-buffered prefetch one step ahead.
// ============================================================
__global__ __launch_bounds__(1024, 4) void enc_kernel(
    const float* __restrict__ Whh,
    const float* __restrict__ Gx,
    float* __restrict__ wsf)
{
    float* hs   = wsf + OFF_HS;
    float* hd   = wsf + OFF_HD;
    float* cdec = wsf + OFF_CT;
    int*   st   = (int*)(wsf + OFF_ST);

    const int b    = blockIdx.x;
    const int tid  = threadIdx.x;
    const int w    = tid >> 6;
    const int lane = tid & 63;
    const int j0   = b * EJPB;
    const int g    = w >> 2;
    const int e0   = (w & 3) * 4;

    __shared__ float bufH[HD];
    __shared__ float g_s[64];
    __shared__ float c_s[EJPB];
    __shared__ float gxbuf[2][64];

    float wreg[4][16];
#pragma unroll
    for (int d = 0; d < 4; ++d) {
        const int grow = g * HD + j0 + e0 + d;
        const float* src = Whh + (size_t)grow * HD + lane;
#pragma unroll
        for (int q = 0; q < 16; ++q) wreg[d][q] = src[q * 64];
    }

    if (tid < EJPB) c_s[tid] = 0.f;

    if (tid >= 64 && tid < 128) {
        const int idx = tid - 64;
        gxbuf[0][idx] = Gx[(size_t)0 * G4H + (idx >> 4) * HD + j0 + (idx & 15)];
    }

    for (int t = 0; t < TLEN; ++t) {
        {
            const float* src = hs + (size_t)t * HD + tid;
            float v = dload(src);
            while (__float_as_uint(v) == SENTINEL) {
                __builtin_amdgcn_s_sleep(POLL_SLEEP);
                v = dload(src);
            }
            bufH[tid] = v;
        }
        __syncthreads();   // barrier A

        if (tid >= 64 && tid < 128 && t + 1 < TLEN) {
            const int idx = tid - 64;
            gxbuf[(t + 1) & 1][idx] =
                Gx[(size_t)(t + 1) * G4H + (idx >> 4) * HD + j0 + (idx & 15)];
        }

        float acc[4];
#pragma unroll
        for (int d = 0; d < 4; ++d) {
            float a = 0.f;
#pragma unroll
            for (int q = 0; q < 16; ++q)
                a = fmaf(wreg[d][q], bufH[q * 64 + lane], a);
#pragma unroll
            for (int off = 32; off > 0; off >>= 1) a += __shfl_down(a, off);
            acc[d] = a;
        }
        if (lane == 0) {
#pragma unroll
            for (int d = 0; d < 4; ++d) g_s[g * 16 + e0 + d] = acc[d];
        }
        __syncthreads();   // barrier B

        if (tid < EJPB) {
            const int j = j0 + tid;
            const float gi = g_s[tid]      + gxbuf[t & 1][tid];
            const float gf = g_s[16 + tid] + gxbuf[t & 1][16 + tid];
            const float gg = g_s[32 + tid] + gxbuf[t & 1][32 + tid];
            const float go = g_s[48 + tid] + gxbuf[t & 1][48 + tid];
            const float i_ = 1.f / (1.f + expf(-gi));
            const float f_ = 1.f / (1.f + expf(-gf));
            const float o_ = 1.f / (1.f + expf(-go));
            const float g2 = tanhf(gg);
            const float c2 = f_ * c_s[tid] + i_ * g2;
            c_s[tid] = c2;
            dstore(hs + (size_t)(t + 1) * HD + j, o_ * tanhf(c2));  // store IS the signal
        }
    }

    if (tid < EJPB) {
        cdec[j0 + tid] = c_s[tid];
        hd[j0 + tid]   = hs[(size_t)TLEN * HD + j0 + tid];
    }
    if (b == 0 && tid == 0) st[0] = BOS_ID;
}

// ============================================================
// Kernel 2b: P[j][t] = dot(W_attn[j, 0:HD], hs[t+1])  — tile GEMM (proven)
// ============================================================
__global__ __launch_bounds__(256) void p_gemm(
    const float* __restrict__ Wattn,
    const float* __restrict__ hs,
    float* __restrict__ P)
{
    __shared__ float As[128][17];
    __shared__ float Bs[128][17];

    const int tid = threadIdx.x;
    const int j0 = blockIdx.x * 128;
    const int t0 = blockIdx.y * 128;
    const int tx = tid & 15;
    const int ty = tid >> 4;
    const int lrow = tid >> 1;
    const int lk   = (tid & 1) * 8;

    float acc[8][8];
#pragma unroll
    for (int i = 0; i < 8; ++i)
#pragma unroll
        for (int j = 0; j < 8; ++j) acc[i][j] = 0.f;

    for (int k0 = 0; k0 < HD; k0 += 16) {
        {
            const float* wa = Wattn + (size_t)(j0 + lrow) * (2 * HD) + k0 + lk;
            float4 v0 = *(const float4*)wa;
            float4 v1 = *(const float4*)(wa + 4);
            As[lrow][lk + 0] = v0.x; As[lrow][lk + 1] = v0.y;
            As[lrow][lk + 2] = v0.z; As[lrow][lk + 3] = v0.w;
            As[lrow][lk + 4] = v1.x; As[lrow][lk + 5] = v1.y;
            As[lrow][lk + 6] = v1.z; As[lrow][lk + 7] = v1.w;
            const float* hb = hs + (size_t)(t0 + lrow + 1) * HD + k0 + lk;
            float4 h0 = *(const float4*)hb;
            float4 h1 = *(const float4*)(hb + 4);
            Bs[lrow][lk + 0] = h0.x; Bs[lrow][lk + 1] = h0.y;
            Bs[lrow][lk + 2] = h0.z; Bs[lrow][lk + 3] = h0.w;
            Bs[lrow][lk + 4] = h1.x; Bs[lrow][lk + 5] = h1.y;
            Bs[lrow][lk + 6] = h1.z; Bs[lrow][lk + 7] = h1.w;
        }
        __syncthreads();
#pragma unroll
        for (int kk = 0; kk < 16; ++kk) {
            float a[8], bv[8];
#pragma unroll
            for (int i = 0; i < 8; ++i) a[i]  = As[ty * 8 + i][kk];
#pragma unroll
            for (int j = 0; j < 8; ++j) bv[j] = Bs[tx * 8 + j][kk];
#pragma unroll
            for (int i = 0; i < 8; ++i)
#pragma unroll
                for (int j = 0; j < 8; ++j)
                    acc[i][j] = fmaf(a[i], bv[j], acc[i][j]);
        }
        __syncthreads();
    }

#pragma unroll
    for (int i = 0; i < 8; ++i) {
        float* dst = P + (size_t)(j0 + ty * 8 + i) * TLEN + t0 + tx * 8;
#pragma unroll
        for (int j = 0; j < 8; ++j) dst[j] = acc[i][j];
    }
}

// ============================================================
// K1: gates — folds previous step's argmax (proven)
// ============================================================
__global__ __launch_bounds__(256) void k_gates(
    const float* __restrict__ embT,
    const float* __restrict__ Wdih,
    const float* __restrict__ Wdhh,
    const float* __restrict__ bdv,
    float* __restrict__ wsf,
    float* __restrict__ out, int s)
{
    float* hd   = wsf + OFF_HD;
    float* cdec = wsf + OFF_CT;
    int*   st   = (int*)(wsf + OFF_ST);
    const float* bmv = wsf + OFF_BMV;
    const int*   bmi = (const int*)(wsf + OFF_BMI);

    const int b    = blockIdx.x;
    const int tid  = threadIdx.x;
    const int w    = tid >> 6;
    const int lane = tid & 63;
    const int j0   = b * JPB;

    const float* hcur = hd + (s & 1) * HD;
    float*       hnxt = hd + ((s + 1) & 1) * HD;

    __shared__ float bufAB[2 * HD];
    __shared__ float g_s[4 * JPB];
    __shared__ float rv[NTHR];
    __shared__ int   ri[NTHR];
    __shared__ int   s_wid;

    for (int i = tid; i < HD; i += NTHR) bufAB[HD + i] = hcur[i];

    if (s == 0) {
        if (tid == 0) s_wid = st[0] & 0xFFFF;
        __syncthreads();
    } else {
        float v1 = bmv[tid]; int i1 = bmi[tid];
        if (tid + 256 < NBLK_L) {
            float v2 = bmv[tid + 256]; int i2 = bmi[tid + 256];
            if (v2 > v1 || (v2 == v1 && i2 < i1)) { v1 = v2; i1 = i2; }
        }
        rv[tid] = v1; ri[tid] = i1;
        __syncthreads();
        for (int s2 = 128; s2 > 0; s2 >>= 1) {
            if (tid < s2) {
                if (rv[tid + s2] > rv[tid] ||
                    (rv[tid + s2] == rv[tid] && ri[tid + s2] < ri[tid])) {
                    rv[tid] = rv[tid + s2]; ri[tid] = ri[tid + s2];
                }
            }
            __syncthreads();
        }
        if (tid == 0) {
            const int nid   = ri[0];
            const int prev  = st[s - 1];
            const int dprev = (prev >> 16) & 1;
            const int dnew  = dprev | (nid == EOS_ID);
            s_wid = nid;
            if (b == 0) {
                out[s - 1] = dprev ? 0.f : (float)nid;
                st[s] = (dnew << 16) | nid;
            }
        }
        __syncthreads();
    }

    const float* x = embT + (size_t)s_wid * HD;
    for (int i = tid; i < HD; i += NTHR) bufAB[i] = x[i];
    __syncthreads();

    const float4* buf4 = (const float4*)bufAB;
#pragma unroll
    for (int d = 0; d < 4; ++d) {
        const int grow = w * HD + j0 + d;
        const float4* wi4 = (const float4*)(Wdih + (size_t)grow * HD);
        const float4* wh4 = (const float4*)(Wdhh + (size_t)grow * HD);
        float4 a4 = make_float4(0.f, 0.f, 0.f, 0.f);
#pragma unroll
        for (int q = 0; q < 4; ++q) {
            float4 wv = wi4[q * 64 + lane], xv = buf4[q * 64 + lane];
            a4.x = fmaf(wv.x, xv.x, a4.x); a4.y = fmaf(wv.y, xv.y, a4.y);
            a4.z = fmaf(wv.z, xv.z, a4.z); a4.w = fmaf(wv.w, xv.w, a4.w);
            float4 wv2 = wh4[q * 64 + lane], hv = buf4[256 + q * 64 + lane];
            a4.x = fmaf(wv2.x, hv.x, a4.x); a4.y = fmaf(wv2.y, hv.y, a4.y);
            a4.z = fmaf(wv2.z, hv.z, a4.z); a4.w = fmaf(wv2.w, hv.w, a4.w);
        }
        float a = (a4.x + a4.y) + (a4.z + a4.w);
#pragma unroll
        for (int off = 32; off > 0; off >>= 1) a += __shfl_down(a, off);
        if (lane == 0) g_s[w * 4 + d] = a;
    }
    __syncthreads();

    if (tid < JPB) {
        const int j = j0 + tid;
        const float gi = g_s[0 * 4 + tid] + bdv[0 * HD + j];
        const float gf = g_s[1 * 4 + tid] + bdv[1 * HD + j];
        const float gg = g_s[2 * 4 + tid] + bdv[2 * HD + j];
        const float go = g_s[3 * 4 + tid] + bdv[3 * HD + j];
        const float i_ = 1.f / (1.f + expf(-gi));
        const float f_ = 1.f / (1.f + expf(-gf));
        const float o_ = 1.f / (1.f + expf(-go));
        const float g2 = tanhf(gg);
        const float c2 = f_ * cdec[j] + i_ * g2;
        cdec[j] = c2;
        hnxt[j] = o_ * tanhf(c2);
    }
}

// K2: attention scores (proven)
__global__ __launch_bounds__(256) void k_scores(float* __restrict__ wsf, int s)
{
    const float* hs = wsf + OFF_HS;
    const float* hnxt = wsf + OFF_HD + (size_t)((s + 1) & 1) * HD;
    float* sc = wsf + OFF_SC;

    const int b    = blockIdx.x;
    const int tid  = threadIdx.x;
    const int w    = tid >> 6;
    const int lane = tid & 63;

    __shared__ float bufH[HD];
    const float4* buf4 = (const float4*)bufH;
    for (int i = tid; i < HD; i += NTHR) bufH[i] = hnxt[i];
    __syncthreads();

#pragma unroll
    for (int d = 0; d < 2; ++d) {
        const int t = b * TPB + w * 2 + d;
        const float4* hr4 = (const float4*)(hs + (size_t)(t + 1) * HD);
        float4 a4 = make_float4(0.f, 0.f, 0.f, 0.f);
#pragma unroll
        for (int q = 0; q < 4; ++q) {
            float4 hv = hr4[q * 64 + lane], bv = buf4[q * 64 + lane];
            a4.x = fmaf(hv.x, bv.x, a4.x); a4.y = fmaf(hv.y, bv.y, a4.y);
            a4.z = fmaf(hv.z, bv.z, a4.z); a4.w = fmaf(hv.w, bv.w, a4.w);
        }
        float a = (a4.x + a4.y) + (a4.z + a4.w);
#pragma unroll
        for (int off = 32; off > 0; off >>= 1) a += __shfl_down(a, off);
        if (lane == 0) sc[t] = a;
    }
}

// K3 (P path): fused softmax + context-via-P + W_attn[:,H:]·ht + tanh (proven)
__global__ __launch_bounds__(256) void k_ctxattn(
    const float* __restrict__ Wattn,
    const float* __restrict__ battn,
    float* __restrict__ wsf,
    const float* __restrict__ P, int s)
{
    const float* sc = wsf + OFF_SC;
    const float* hnxt = wsf + OFF_HD + (size_t)((s + 1) & 1) * HD;
    float* htn = wsf + OFF_HTN;

    const int b    = blockIdx.x;
    const int tid  = threadIdx.x;
    const int w    = tid >> 6;
    const int lane = tid & 63;
    const int j0   = b * JPB;

    __shared__ float sc_s[TLEN];
    __shared__ float bufH[HD];
    __shared__ float red[NTHR];

    for (int t = tid; t < TLEN; t += NTHR) sc_s[t] = sc[t];
    for (int i = tid; i < HD; i += NTHR) bufH[i] = hnxt[i];
    __syncthreads();

    float lm = -INFINITY;
    for (int t = tid; t < TLEN; t += NTHR) lm = fmaxf(lm, sc_s[t]);
    red[tid] = lm; __syncthreads();
    for (int s2 = NTHR / 2; s2 > 0; s2 >>= 1) {
        if (tid < s2) red[tid] = fmaxf(red[tid], red[tid + s2]);
        __syncthreads();
    }
    const float m = red[0]; __syncthreads();
    float lz = 0.f;
    for (int t = tid; t < TLEN; t += NTHR) lz += __expf(sc_s[t] - m);
    red[tid] = lz; __syncthreads();
    for (int s2 = NTHR / 2; s2 > 0; s2 >>= 1) {
        if (tid < s2) red[tid] += red[tid + s2];
        __syncthreads();
    }
    const float Zi = 1.f / red[0]; __syncthreads();

    const int j = j0 + w;
    float a = 0.f;
    const float* Pr = P + (size_t)j * TLEN;
#pragma unroll
    for (int it = 0; it < TLEN / 64; ++it) {
        const int t = lane + it * 64;
        a = fmaf(__expf(sc_s[t] - m) * Zi, Pr[t], a);
    }
    const float4* wr4 = (const float4*)(Wattn + (size_t)j * (2 * HD) + HD);
    const float4* buf4 = (const float4*)bufH;
    float4 a4 = make_float4(0.f, 0.f, 0.f, 0.f);
#pragma unroll
    for (int q = 0; q < 4; ++q) {
        float4 wv = wr4[q * 64 + lane], hv = buf4[q * 64 + lane];
        a4.x = fmaf(wv.x, hv.x, a4.x); a4.y = fmaf(wv.y, hv.y, a4.y);
        a4.z = fmaf(wv.z, hv.z, a4.z); a4.w = fmaf(wv.w, hv.w, a4.w);
    }
    a += (a4.x + a4.y) + (a4.z + a4.w);
#pragma unroll
    for (int off = 32; off > 0; off >>= 1) a += __shfl_down(a, off);
    if (lane == 0) htn[j] = tanhf(a + battn[j]);
}

// K3-fallback: softmax + context slice — proven
__global__ __launch_bounds__(256) void k_ctx_fb(float* __restrict__ wsf)
{
    const float* hs = wsf + OFF_HS;
    const float* sc = wsf + OFF_SC;
    float* dctx = wsf + OFF_DC;

    const int b    = blockIdx.x;
    const int tid  = threadIdx.x;
    const int w    = tid >> 6;
    const int lane = tid & 63;
    const int j0   = b * JPB;

    __shared__ float sc_s[TLEN];
    __shared__ float red[NTHR];

    for (int t = tid; t < TLEN; t += NTHR) sc_s[t] = sc[t];
    __syncthreads();

    float lm = -INFINITY;
    for (int t = tid; t < TLEN; t += NTHR) lm = fmaxf(lm, sc_s[t]);
    red[tid] = lm; __syncthreads();
    for (int s2 = NTHR / 2; s2 > 0; s2 >>= 1) {
        if (tid < s2) red[tid] = fmaxf(red[tid], red[tid + s2]);
        __syncthreads();
    }
    const float m = red[0]; __syncthreads();
    float lz = 0.f;
    for (int t = tid; t < TLEN; t += NTHR) lz += __expf(sc_s[t] - m);
    red[tid] = lz; __syncthreads();
    for (int s2 = NTHR / 2; s2 > 0; s2 >>= 1) {
        if (tid < s2) red[tid] += red[tid + s2];
        __syncthreads();
    }
    const float Zi = 1.f / red[0]; __syncthreads();

    const int j = j0 + w;
    float a = 0.f;
#pragma unroll
    for (int it = 0; it < TLEN / 64; ++it) {
        const int t = lane + it * 64;
        a = fmaf(__expf(sc_s[t] - m) * Zi, hs[(size_t)(t + 1) * HD + j], a);
    }
#pragma unroll
    for (int off = 32; off > 0; off >>= 1) a += __shfl_down(a, off);
    if (lane == 0) dctx[j] = a;
}

// K4-fallback: ht_new (proven)
__global__ __launch_bounds__(256) void k_attn(
    const float* __restrict__ Wattn,
    const float* __restrict__ battn,
    float* __restrict__ wsf, int s)
{
    const float* dctx = wsf + OFF_DC;
    const float* hnxt = wsf + OFF_HD + (size_t)((s + 1) & 1) * HD;
    float* htn = wsf + OFF_HTN;

    const int b    = blockIdx.x;
    const int tid  = threadIdx.x;
    const int w    = tid >> 6;
    const int lane = tid & 63;
    const int j0   = b * JPB;

    __shared__ float bufAB[2 * HD];
    const float4* buf4 = (const float4*)bufAB;
    for (int i = tid; i < HD; i += NTHR) {
        bufAB[i]      = dctx[i];
        bufAB[HD + i] = hnxt[i];
    }
    __syncthreads();

    const int j = j0 + w;
    const float4* wr4 = (const float4*)(Wattn + (size_t)j * (2 * HD));
    float4 a4 = make_float4(0.f, 0.f, 0.f, 0.f);
#pragma unroll
    for (int q = 0; q < 8; ++q) {
        float4 wv = wr4[q * 64 + lane], bv = buf4[q * 64 + lane];
        a4.x = fmaf(wv.x, bv.x, a4.x); a4.y = fmaf(wv.y, bv.y, a4.y);
        a4.z = fmaf(wv.z, bv.z, a4.z); a4.w = fmaf(wv.w, bv.w, a4.w);
    }
    float a = (a4.x + a4.y) + (a4.z + a4.w);
#pragma unroll
    for (int off = 32; off > 0; off >>= 1) a += __shfl_down(a, off);
    if (lane == 0) htn[j] = tanhf(a + battn[j]);
}

// K5: logits + per-block argmax, with done fast-path (proven)
__global__ __launch_bounds__(256) void k_logits(
    const float* __restrict__ Wout,
    const float* __restrict__ bout,
    float* __restrict__ wsf,
    float* __restrict__ out, int s)
{
    const float* htn = wsf + OFF_HTN;
    float* bmv = wsf + OFF_BMV;
    int*   bmi = (int*)(wsf + OFF_BMI);
    const int* st = (const int*)(wsf + OFF_ST);

    const int b    = blockIdx.x;
    const int tid  = threadIdx.x;
    const int w    = tid >> 6;
    const int lane = tid & 63;

    __shared__ float bufH[HD];
    __shared__ float red[4];
    __shared__ int   redi[4];
    const float4* buf4 = (const float4*)bufH;

    const int donev = (st[s] >> 16) & 1;

    if (donev) {
        if (tid < 64) out[NSTEP + (size_t)s * VOUTN + b * 64 + tid] = 0.f;
        if (tid == 0) { bmv[b] = -INFINITY; bmi[b] = 0; }
        return;
    }

    for (int i = tid; i < HD; i += NTHR) bufH[i] = htn[i];
    __syncthreads();

    const int rbeg = b * 64 + w * RPW_L;
    float bv = -INFINITY; int bi = 0x7fffffff;
    for (int r = rbeg; r < rbeg + RPW_L; r += 2) {
        const float4* w0 = (const float4*)(Wout + (size_t)r * HD);
        const float4* w1 = (const float4*)(Wout + (size_t)(r + 1) * HD);
        float4 a04 = make_float4(0.f, 0.f, 0.f, 0.f);
        float4 a14 = make_float4(0.f, 0.f, 0.f, 0.f);
#pragma unroll
        for (int q = 0; q < 4; ++q) {
            float4 hv = buf4[q * 64 + lane];
            float4 x0 = w0[q * 64 + lane];
            float4 x1 = w1[q * 64 + lane];
            a04.x = fmaf(x0.x, hv.x, a04.x); a04.y = fmaf(x0.y, hv.y, a04.y);
            a04.z = fmaf(x0.z, hv.z, a04.z); a04.w = fmaf(x0.w, hv.w, a04.w);
            a14.x = fmaf(x1.x, hv.x, a14.x); a14.y = fmaf(x1.y, hv.y, a14.y);
            a14.z = fmaf(x1.z, hv.z, a14.z); a14.w = fmaf(x1.w, hv.w, a14.w);
        }
        float a0 = (a04.x + a04.y) + (a04.z + a04.w);
        float a1 = (a14.x + a14.y) + (a14.z + a14.w);
#pragma unroll
        for (int off = 32; off > 0; off >>= 1) {
            a0 += __shfl_down(a0, off);
            a1 += __shfl_down(a1, off);
        }
        if (lane == 0) {
            a0 += bout[r];
            a1 += bout[r + 1];
            out[NSTEP + (size_t)s * VOUTN + r]     = a0;
            out[NSTEP + (size_t)s * VOUTN + r + 1] = a1;
            if (a0 > bv) { bv = a0; bi = r; }
            if (a1 > bv) { bv = a1; bi = r + 1; }
        }
    }
    if (lane == 0) { red[w] = bv; redi[w] = bi; }
    __syncthreads();
    if (tid == 0) {
        float v = red[0]; int ii = redi[0];
#pragma unroll
        for (int q = 1; q < 4; ++q)
            if (red[q] > v || (red[q] == v && redi[q] < ii)) { v = red[q]; ii = redi[q]; }
        bmv[b] = v; bmi[b] = ii;
    }
}

// K6 (final only): global argmax for step 49's token
__global__ __launch_bounds__(256) void k_amax_final(
    float* __restrict__ wsf, float* __restrict__ out)
{
    const float* bmv = wsf + OFF_BMV;
    const int*   bmi = (const int*)(wsf + OFF_BMI);
    const int*   st  = (const int*)(wsf + OFF_ST);

    const int tid = threadIdx.x;
    __shared__ float red[NTHR];
    __shared__ int   redi[NTHR];

    float v1 = bmv[tid]; int i1 = bmi[tid];
    if (tid + 256 < NBLK_L) {
        float v2 = bmv[tid + 256]; int i2 = bmi[tid + 256];
        if (v2 > v1 || (v2 == v1 && i2 < i1)) { v1 = v2; i1 = i2; }
    }
    red[tid] = v1; redi[tid] = i1;
    __syncthreads();
    for (int s2 = 128; s2 > 0; s2 >>= 1) {
        if (tid < s2) {
            if (red[tid + s2] > red[tid] ||
                (red[tid + s2] == red[tid] && redi[tid + s2] < redi[tid])) {
                red[tid] = red[tid + s2]; redi[tid] = redi[tid + s2];
            }
        }
        __syncthreads();
    }
    if (tid == 0) {
        const int nid   = redi[0];
        const int donev = (st[NSTEP - 1] >> 16) & 1;
        out[NSTEP - 1] = donev ? 0.f : (float)nid;
    }
}

extern "C" void kernel_launch(void* const* d_in, const int* in_sizes, int n_in,
                              void* d_out, int out_size, void* d_ws, size_t ws_size,
                              hipStream_t stream) {
    (void)in_sizes; (void)n_in; (void)out_size;
    const int*   src_ids = (const int*)  d_in[0];
    const float* emb_in  = (const float*)d_in[1];
    const float* We_ih   = (const float*)d_in[2];
    const float* We_hh   = (const float*)d_in[3];
    const float* be      = (const float*)d_in[4];
    const float* emb_tgt = (const float*)d_in[5];
    const float* Wd_ih   = (const float*)d_in[6];
    const float* Wd_hh   = (const float*)d_in[7];
    const float* bd      = (const float*)d_in[8];
    const float* W_attn  = (const float*)d_in[9];
    const float* b_attn  = (const float*)d_in[10];
    const float* W_out   = (const float*)d_in[11];
    const float* b_out   = (const float*)d_in[12];

    float* outp = (float*)d_out;
    float* wsf  = (float*)d_ws;

    const bool use_P = (ws_size >= WS_NEED_P);

    // deterministic init every call: hs row 0 zeros + rows 1..TLEN sentinel
    fill_sentinel<<<TLEN + 1, 256, 0, stream>>>(wsf + OFF_HS);

    // Phase 1: Gx = X @ We_ih^T + be
    dim3 g1(TLEN / 128, G4H / 128);
    gx_gemm<<<g1, 256, 0, stream>>>(src_ids, emb_in, We_ih, be, wsf + OFF_GX);

    // Phase 2: encoder (cooperative; sentinel data-poll inside)
    {
        const float* a_Whh = We_hh;
        const float* a_Gx  = wsf + OFF_GX;
        float* a_ws  = wsf;
        void* args[] = { &a_Whh, &a_Gx, &a_ws };
        hipLaunchCooperativeKernel(reinterpret_cast<void*>(enc_kernel),
                                   dim3(ENBLK), dim3(ENTHR), args, 0, stream);
    }

    // Phase 2b: P = W_attn[:, :H] @ hs[1:].T  (if workspace allows)
    if (use_P)
        p_gemm<<<dim3(HD / 128, TLEN / 128), 256, 0, stream>>>(
            W_attn, wsf + OFF_HS, wsf + OFF_P);

    // Phase 3: decoder — 4 kernels per step (P path) or 5 (fallback)
    for (int s = 0; s < NSTEP; ++s) {
        k_gates <<<NBLK,   NTHR, 0, stream>>>(emb_tgt, Wd_ih, Wd_hh, bd, wsf, outp, s);
        k_scores<<<NBLK,   NTHR, 0, stream>>>(wsf, s);
        if (use_P) {
            k_ctxattn<<<NBLK, NTHR, 0, stream>>>(W_attn, b_attn, wsf, wsf + OFF_P, s);
        } else {
            k_ctx_fb<<<NBLK, NTHR, 0, stream>>>(wsf);
            k_attn  <<<NBLK, NTHR, 0, stream>>>(W_attn, b_attn, wsf, s);
        }
        k_logits<<<NBLK_L, NTHR, 0, stream>>>(W_out, b_out, wsf, outp, s);
    }
    k_amax_final<<<1, NTHR, 0, stream>>>(wsf, outp);
}